// Round 7
// baseline (261.137 us; speedup 1.0000x reference)
//
#include <hip/hip_runtime.h>
#include <hip/hip_bf16.h>
#include <cstddef>
#include <cstdint>

#define T_TOK 4096
#define H_DIM 2048
#define E_NUM 8
#define I_DIM 1024
#define TWO_I 2048
#define MROWS 6144      // worst-case 256-padded slot rows
#define MT_MAX 24       // MROWS/256

typedef __attribute__((ext_vector_type(8))) short bf16x8;
typedef __attribute__((ext_vector_type(4))) float f32x4;
typedef __attribute__((ext_vector_type(4))) int   i32x4;

// -------- workspace layout (bytes); ws >= 128 MiB proven --------
#define WS_SCALE   0            // f32[4096]
#define WS_COUNTS  16384        // int[8]
#define WS_OFFP    16448        // int[9] (256-padded prefix)
#define WS_BUCKETS 16512        // int[8*4096]  ends 147584
#define WS_SLOTTOK 147584       // int[6144]    ends 172160
#define WS_XSG     (1u<<20)     // bf16[6144*2048] = 25.2 MB
#define WS_ACT     (28u<<20)    // bf16[6144*1024] = 12.6 MB
#define WS_WT      (42u<<20)    // shared w1t/w2t region, 67.1 MB

__device__ __forceinline__ short f2bf(float f) {
    uint32_t u = __builtin_bit_cast(uint32_t, f);
    u += 0x7fffu + ((u >> 16) & 1u);
    return (short)(u >> 16);
}

__device__ __forceinline__ void gload16(const void* g, void* l) {
    __builtin_amdgcn_global_load_lds(
        (const __attribute__((address_space(1))) void*)g,
        (__attribute__((address_space(3))) void*)l, 16, 0, 0);
}

// ---------------- router (vectorized float4, wave per token) ----------------
__global__ __launch_bounds__(256) void router_kernel(
    const float* __restrict__ x, const float* __restrict__ gw,
    float* __restrict__ scale, int* __restrict__ counts, int* __restrict__ buckets)
{
    const int wid  = threadIdx.x >> 6;
    const int lane = threadIdx.x & 63;
    const int t = blockIdx.x * 4 + wid;
    if (t >= T_TOK) return;

    float4 a4[E_NUM];
#pragma unroll
    for (int e = 0; e < E_NUM; ++e) a4[e] = make_float4(0.f, 0.f, 0.f, 0.f);

    const float4* xr  = (const float4*)(x + (size_t)t * H_DIM);
    const float4* gwv = (const float4*)gw;
#pragma unroll
    for (int it = 0; it < 8; ++it) {
        const int idx = lane + it * 64;
        float4 xv = xr[idx];
#pragma unroll
        for (int e = 0; e < E_NUM; ++e) {
            float4 wv = gwv[e * 512 + idx];
            a4[e].x = fmaf(xv.x, wv.x, a4[e].x);
            a4[e].y = fmaf(xv.y, wv.y, a4[e].y);
            a4[e].z = fmaf(xv.z, wv.z, a4[e].z);
            a4[e].w = fmaf(xv.w, wv.w, a4[e].w);
        }
    }
    float acc[E_NUM];
#pragma unroll
    for (int e = 0; e < E_NUM; ++e) {
        float v = (a4[e].x + a4[e].y) + (a4[e].z + a4[e].w);
#pragma unroll
        for (int off = 32; off > 0; off >>= 1) v += __shfl_xor(v, off);
        acc[e] = v;
    }
    if (lane == 0) {
        int best = 0; float bv = acc[0];
#pragma unroll
        for (int e = 1; e < E_NUM; ++e) { if (acc[e] > bv) { bv = acc[e]; best = e; } }
        scale[t] = 1.f / (1.f + expf(-bv));
        int pos = atomicAdd(&counts[best], 1);
        buckets[best * T_TOK + pos] = t;
    }
}

// ---------------- 256-padded prefix offsets ----------------
__global__ void offs_kernel(const int* __restrict__ counts, int* __restrict__ offP) {
    if (threadIdx.x == 0) {
        int run = 0;
#pragma unroll
        for (int e = 0; e < E_NUM; ++e) { offP[e] = run; run += (counts[e] + 255) & ~255; }
        offP[E_NUM] = run;
    }
}

// ---------------- gather: xsg[slot] = bf16(scale[tok] * x[tok]) ----------------
__global__ __launch_bounds__(256) void gather_kernel(
    const float* __restrict__ x, const float* __restrict__ scale,
    const int* __restrict__ counts, const int* __restrict__ offP,
    const int* __restrict__ buckets, short* __restrict__ xsg,
    int* __restrict__ slot_tok)
{
    const int r = blockIdx.x;
    int e = 0;
#pragma unroll
    for (int k = 1; k < E_NUM; ++k) if (r >= offP[k]) e = k;
    const int pos = r - offP[e];
    const bool valid = (r < offP[E_NUM]) && (pos < counts[e]);
    const int tok = valid ? buckets[e * T_TOK + pos] : -1;
    if (threadIdx.x == 0) slot_tok[r] = tok;

    short* orow = xsg + (size_t)r * H_DIM + threadIdx.x * 8;
    if (!valid) {
        i32x4 z = {0, 0, 0, 0};
        *(i32x4*)orow = z;
        return;
    }
    const float sc = scale[tok];
    const float* xr = x + (size_t)tok * H_DIM + threadIdx.x * 8;
    float4 a = *(const float4*)xr;
    float4 b = *(const float4*)(xr + 4);
    short o[8] __attribute__((aligned(16)));
    o[0] = f2bf(a.x * sc); o[1] = f2bf(a.y * sc);
    o[2] = f2bf(a.z * sc); o[3] = f2bf(a.w * sc);
    o[4] = f2bf(b.x * sc); o[5] = f2bf(b.y * sc);
    o[6] = f2bf(b.z * sc); o[7] = f2bf(b.w * sc);
    *(i32x4*)orow = *(const i32x4*)o;
}

// ---------------- weight transpose + bf16 convert ----------------
__global__ __launch_bounds__(256) void transpose_cvt_kernel(
    const float* __restrict__ src, short* __restrict__ dst, int K, int N)
{
    __shared__ float s[64][65];
    const int e  = blockIdx.z;
    const int k0 = blockIdx.x * 64;
    const int n0 = blockIdx.y * 64;
    const int t  = threadIdx.x;

    const float* S = src + ((size_t)e * K + k0) * N + n0;
    const int kr = t >> 4, nc = (t & 15) * 4;
#pragma unroll
    for (int i = 0; i < 4; ++i) {
        float4 v = *(const float4*)(S + (size_t)(kr + i * 16) * N + nc);
        s[kr + i * 16][nc + 0] = v.x;
        s[kr + i * 16][nc + 1] = v.y;
        s[kr + i * 16][nc + 2] = v.z;
        s[kr + i * 16][nc + 3] = v.w;
    }
    __syncthreads();

    const int nr = t >> 2, kc = (t & 3) * 16;
    short tmp[16] __attribute__((aligned(16)));
#pragma unroll
    for (int j = 0; j < 16; ++j) tmp[j] = f2bf(s[kc + j][nr]);
    short* D = dst + ((size_t)e * N + n0 + nr) * K + k0 + kc;
    *(i32x4*)D       = *(const i32x4*)tmp;
    *(i32x4*)(D + 8) = *(const i32x4*)(tmp + 8);
}

// ================== 256x256 grouped MFMA GEMMs, half-tile (K=32) pipeline ====
// 8 waves (2M x 4N). LDS: 4 cyclic half-slots x (A 16KB + B 16KB) = 128KB.
// Slot layout [256 rows][32 k] bf16; 16B-chunk XOR swizzle c' = c ^ ((row>>1)&3)
// staged via inverse-permuted global source (involution; both-sides rule).
// Pipeline: stage half h+3 at top of iter h; vmcnt(8) (tail 4/0) drains only
// the oldest unit -> 2-3 halves in flight, issue-to-use ~3 half-iters.

#define LDAX(S, MQ, mf) (*(const bf16x8*)&sA[S][(wm*128 + (MQ)*64 + (mf)*16 + lm)*32 + kperm])
#define LDBX(S, NQ, nf) (*(const bf16x8*)&sB[S][(wn*64 + (NQ)*32 + (nf)*16 + lm)*32 + kperm])

#define Q8(MQ, NQ, AV, BV)                                                     \
    __builtin_amdgcn_s_setprio(1);                                             \
    _Pragma("unroll") for (int mf = 0; mf < 4; ++mf)                           \
      _Pragma("unroll") for (int nf = 0; nf < 2; ++nf)                         \
        acc[(MQ) * 4 + mf][(NQ) * 2 + nf] =                                    \
            __builtin_amdgcn_mfma_f32_16x16x32_bf16(AV[mf], BV[nf],            \
                acc[(MQ) * 4 + mf][(NQ) * 2 + nf], 0, 0, 0);                   \
    __builtin_amdgcn_s_setprio(0);

#define COMPUTE_HALF(S)                                                        \
  {                                                                            \
    __builtin_amdgcn_sched_barrier(0);                                         \
    bf16x8 af[4], b0[2], b1[2];                                                \
    _Pragma("unroll") for (int mf = 0; mf < 4; ++mf) af[mf] = LDAX(S, 0, mf);  \
    _Pragma("unroll") for (int nf = 0; nf < 2; ++nf) b0[nf] = LDBX(S, 0, nf);  \
    Q8(0, 0, af, b0)                                                           \
    _Pragma("unroll") for (int nf = 0; nf < 2; ++nf) b1[nf] = LDBX(S, 1, nf);  \
    Q8(0, 1, af, b1)                                                           \
    _Pragma("unroll") for (int mf = 0; mf < 4; ++mf) af[mf] = LDAX(S, 1, mf);  \
    Q8(1, 1, af, b1)                                                           \
    Q8(1, 0, af, b0)                                                           \
    __builtin_amdgcn_sched_barrier(0);                                         \
  }

#define GEMM_PIPELINE(NH)                                                      \
    stage_half(0, 0); stage_half(1, 1); stage_half(2, 2);                      \
    _Pragma("unroll 4")                                                        \
    for (int h = 0; h < (NH); ++h) {                                           \
        const int rem = (NH) - 1 - h;                                          \
        if (rem >= 3) stage_half((h + 3) & 3, h + 3);                          \
        if (rem >= 2)      asm volatile("s_waitcnt vmcnt(8)" ::: "memory");    \
        else if (rem == 1) asm volatile("s_waitcnt vmcnt(4)" ::: "memory");    \
        else               asm volatile("s_waitcnt vmcnt(0)" ::: "memory");    \
        __builtin_amdgcn_s_barrier();                                          \
        COMPUTE_HALF(h & 3);                                                   \
        __builtin_amdgcn_s_barrier();                                          \
    }

__global__ __launch_bounds__(512) void gemm1_8ph_kernel(
    const short* __restrict__ xsg, const short* __restrict__ w1t,
    const int* __restrict__ offP, short* __restrict__ act)
{
    __shared__ short sA[4][8192];   // [slot][row*32 + k], 256 rows x 32 k
    __shared__ short sB[4][8192];

    const int bid = blockIdx.x;                      // 192 = 8 * 24
    const int wg  = (bid & 7) * MT_MAX + (bid >> 3); // bijective XCD swizzle
    const int nt  = wg / MT_MAX;
    const int mt  = wg % MT_MAX;
    const int m0  = mt << 8;
    if (m0 >= offP[E_NUM]) return;
    const int f0  = nt << 7;

    int e = 0;
#pragma unroll
    for (int k = 1; k < E_NUM; ++k) if (m0 >= offP[k]) e = k;

    const int tid = threadIdx.x, lane = tid & 63, w = tid >> 6;
    const int wm = w >> 2, wn = w & 3;
    const int lm = lane & 15, lg = lane >> 4;
    const int kperm = (lg ^ ((lm >> 1) & 3)) << 3;   // shorts

    // stage geometry: unit i in {0,1}: row = w*32 + i*16 + (L>>2),
    // src 16B-chunk = (L&3) ^ ((L>>3)&3)  (inverse of read XOR)
    const int rA    = w * 32 + (lane >> 2);
    const int cperm = ((lane & 3) ^ ((lane >> 3) & 3)) * 8;

    const short* srcA0 = xsg + (size_t)(m0 + rA     ) * H_DIM + cperm;
    const short* srcA1 = xsg + (size_t)(m0 + rA + 16) * H_DIM + cperm;

    // B u/g interleave in 16-row chunks:
    //  grow(rb) = ((rb>>4)&1)*I + f0 + ((rb>>7)*4 + ((rb>>5)&3))*16 + (rb&15)
    auto growf = [&](int rb) {
        return ((rb >> 4) & 1) * I_DIM + f0
             + (((rb >> 7) << 2) + ((rb >> 5) & 3)) * 16 + (rb & 15);
    };
    const short* srcB0 = w1t + ((size_t)e * TWO_I + growf(rA     )) * H_DIM + cperm;
    const short* srcB1 = w1t + ((size_t)e * TWO_I + growf(rA + 16)) * H_DIM + cperm;

    auto stage_half = [&](int slot, int hh) {
        const int kb = hh * 32;
        gload16(srcA0 + kb, &sA[slot][w * 1024      ]);
        gload16(srcA1 + kb, &sA[slot][w * 1024 + 512]);
        gload16(srcB0 + kb, &sB[slot][w * 1024      ]);
        gload16(srcB1 + kb, &sB[slot][w * 1024 + 512]);
    };

    f32x4 acc[8][4];
#pragma unroll
    for (int i = 0; i < 8; ++i)
#pragma unroll
        for (int j = 0; j < 4; ++j) acc[i][j] = (f32x4){0.f, 0.f, 0.f, 0.f};

    GEMM_PIPELINE(H_DIM / 32)

    // epilogue: act = up * gate * sigmoid(gate)
#pragma unroll
    for (int a = 0; a < 8; ++a) {
        const int mrow = m0 + wm * 128 + (a >> 2) * 64 + (a & 3) * 16 + lg * 4;
#pragma unroll
        for (int q = 0; q < 2; ++q) {
            const int fcol = f0 + (wn * 2 + q) * 16 + lm;
#pragma unroll
            for (int r = 0; r < 4; ++r) {
                float up = acc[a][q * 2][r];
                float gt = acc[a][q * 2 + 1][r];
                float v  = up * gt / (1.f + expf(-gt));
                act[(size_t)(mrow + r) * I_DIM + fcol] = f2bf(v);
            }
        }
    }
}

__global__ __launch_bounds__(512) void gemm2_8ph_kernel(
    const short* __restrict__ actm, const short* __restrict__ w2t,
    const int* __restrict__ offP, const int* __restrict__ slot_tok,
    float* __restrict__ out)
{
    __shared__ short sA[4][8192];
    __shared__ short sB[4][8192];

    const int bid = blockIdx.x;
    const int wg  = (bid & 7) * MT_MAX + (bid >> 3);
    const int nt  = wg / MT_MAX;
    const int mt  = wg % MT_MAX;
    const int m0  = mt << 8;
    if (m0 >= offP[E_NUM]) return;
    const int h0  = nt << 8;

    int e = 0;
#pragma unroll
    for (int k = 1; k < E_NUM; ++k) if (m0 >= offP[k]) e = k;

    const int tid = threadIdx.x, lane = tid & 63, w = tid >> 6;
    const int wm = w >> 2, wn = w & 3;
    const int lm = lane & 15, lg = lane >> 4;
    const int kperm = (lg ^ ((lm >> 1) & 3)) << 3;

    const int rA    = w * 32 + (lane >> 2);
    const int cperm = ((lane & 3) ^ ((lane >> 3) & 3)) * 8;

    const short* srcA0 = actm + (size_t)(m0 + rA     ) * I_DIM + cperm;
    const short* srcA1 = actm + (size_t)(m0 + rA + 16) * I_DIM + cperm;
    const short* srcB0 = w2t + ((size_t)e * H_DIM + h0 + rA     ) * I_DIM + cperm;
    const short* srcB1 = w2t + ((size_t)e * H_DIM + h0 + rA + 16) * I_DIM + cperm;

    auto stage_half = [&](int slot, int hh) {
        const int kb = hh * 32;
        gload16(srcA0 + kb, &sA[slot][w * 1024      ]);
        gload16(srcA1 + kb, &sA[slot][w * 1024 + 512]);
        gload16(srcB0 + kb, &sB[slot][w * 1024      ]);
        gload16(srcB1 + kb, &sB[slot][w * 1024 + 512]);
    };

    f32x4 acc[8][4];
#pragma unroll
    for (int i = 0; i < 8; ++i)
#pragma unroll
        for (int j = 0; j < 4; ++j) acc[i][j] = (f32x4){0.f, 0.f, 0.f, 0.f};

    GEMM_PIPELINE(I_DIM / 32)

    // epilogue: scatter rows to out via slot_tok
#pragma unroll
    for (int a = 0; a < 8; ++a) {
        const int mloc = wm * 128 + (a >> 2) * 64 + (a & 3) * 16 + lg * 4;
#pragma unroll
        for (int r = 0; r < 4; ++r) {
            const int tok = slot_tok[m0 + mloc + r];
            if (tok < 0) continue;
            float* orow = out + (size_t)tok * H_DIM + h0;
#pragma unroll
            for (int b = 0; b < 4; ++b) {
                const int hcol = wn * 64 + (b >> 1) * 32 + (b & 1) * 16 + lm;
                orow[hcol] = acc[a][b][r];
            }
        }
    }
}

extern "C" void kernel_launch(void* const* d_in, const int* in_sizes, int n_in,
                              void* d_out, int out_size, void* d_ws, size_t ws_size,
                              hipStream_t stream) {
    const float* x   = (const float*)d_in[0];
    const float* gw  = (const float*)d_in[1];
    const float* gup = (const float*)d_in[2];
    const float* dw  = (const float*)d_in[3];
    float* out = (float*)d_out;

    char* ws = (char*)d_ws;
    float* scale    = (float*)(ws + WS_SCALE);
    int*   counts   = (int*)(ws + WS_COUNTS);
    int*   offP     = (int*)(ws + WS_OFFP);
    int*   buckets  = (int*)(ws + WS_BUCKETS);
    int*   slot_tok = (int*)(ws + WS_SLOTTOK);
    short* xsg      = (short*)(ws + WS_XSG);
    short* act      = (short*)(ws + WS_ACT);
    short* wt       = (short*)(ws + WS_WT);    // shared: w1t then w2t

    hipMemsetAsync(counts, 0, E_NUM * sizeof(int), stream);
    router_kernel<<<T_TOK / 4, 256, 0, stream>>>(x, gw, scale, counts, buckets);
    offs_kernel<<<1, 64, 0, stream>>>(counts, offP);
    gather_kernel<<<MROWS, 256, 0, stream>>>(x, scale, counts, offP, buckets, xsg, slot_tok);

    // w1t = transpose(gate_up_weight) bf16, then GEMM1 (+SwiGLU)
    dim3 gt1(H_DIM / 64, TWO_I / 64, E_NUM);
    transpose_cvt_kernel<<<gt1, 256, 0, stream>>>(gup, wt, H_DIM, TWO_I);
    gemm1_8ph_kernel<<<8 * MT_MAX, 512, 0, stream>>>(xsg, wt, offP, act);

    // w2t = transpose(down_weight) bf16 (reuses region), then GEMM2 (+scatter)
    dim3 gt2(I_DIM / 64, H_DIM / 64, E_NUM);
    transpose_cvt_kernel<<<gt2, 256, 0, stream>>>(dw, wt, I_DIM, H_DIM);
    gemm2_8ph_kernel<<<8 * MT_MAX, 512, 0, stream>>>(act, wt, offP, slot_tok, out);
}

// Round 8
// 237.847 us; speedup vs baseline: 1.0979x; 1.0979x over previous
//
#include <hip/hip_runtime.h>
#include <hip/hip_bf16.h>
#include <cstddef>
#include <cstdint>

#define T_TOK 4096
#define H_DIM 2048
#define E_NUM 8
#define I_DIM 1024
#define TWO_I 2048
#define MROWS 5120      // worst-case 128-padded slot rows
#define MT    40        // MROWS/128 M-tiles

typedef __attribute__((ext_vector_type(8))) short bf16x8;
typedef __attribute__((ext_vector_type(4))) float f32x4;
typedef __attribute__((ext_vector_type(4))) int   i32x4;

// -------- workspace layout (bytes); ws >= 128 MiB proven --------
#define WS_SCALE   0            // f32[4096]
#define WS_COUNTS  16384        // int[8]
#define WS_OFFP    16448        // int[9] (128-padded prefix)
#define WS_BUCKETS 16512        // int[8*4096]  ends 147584
#define WS_SLOTTOK 147584       // int[5120]    ends 168064
#define WS_XSG     (1u<<20)     // bf16[5120*2048] = 20.97 MB
#define WS_ACT     (23u<<20)    // bf16[5120*1024] = 10.49 MB
#define WS_WT      (34u<<20)    // shared w1t/w2t region, 67.11 MB

__device__ __forceinline__ short f2bf(float f) {
    uint32_t u = __builtin_bit_cast(uint32_t, f);
    u += 0x7fffu + ((u >> 16) & 1u);
    return (short)(u >> 16);
}

__device__ __forceinline__ void gload16(const void* g, void* l) {
    __builtin_amdgcn_global_load_lds(
        (const __attribute__((address_space(1))) void*)g,
        (__attribute__((address_space(3))) void*)l, 16, 0, 0);
}

// ---------------- router (vectorized float4, wave per token) ----------------
__global__ __launch_bounds__(256) void router_kernel(
    const float* __restrict__ x, const float* __restrict__ gw,
    float* __restrict__ scale, int* __restrict__ counts, int* __restrict__ buckets)
{
    const int wid  = threadIdx.x >> 6;
    const int lane = threadIdx.x & 63;
    const int t = blockIdx.x * 4 + wid;
    if (t >= T_TOK) return;

    float4 a4[E_NUM];
#pragma unroll
    for (int e = 0; e < E_NUM; ++e) a4[e] = make_float4(0.f, 0.f, 0.f, 0.f);

    const float4* xr  = (const float4*)(x + (size_t)t * H_DIM);
    const float4* gwv = (const float4*)gw;
#pragma unroll
    for (int it = 0; it < 8; ++it) {
        const int idx = lane + it * 64;
        float4 xv = xr[idx];
#pragma unroll
        for (int e = 0; e < E_NUM; ++e) {
            float4 wv = gwv[e * 512 + idx];
            a4[e].x = fmaf(xv.x, wv.x, a4[e].x);
            a4[e].y = fmaf(xv.y, wv.y, a4[e].y);
            a4[e].z = fmaf(xv.z, wv.z, a4[e].z);
            a4[e].w = fmaf(xv.w, wv.w, a4[e].w);
        }
    }
    float acc[E_NUM];
#pragma unroll
    for (int e = 0; e < E_NUM; ++e) {
        float v = (a4[e].x + a4[e].y) + (a4[e].z + a4[e].w);
#pragma unroll
        for (int off = 32; off > 0; off >>= 1) v += __shfl_xor(v, off);
        acc[e] = v;
    }
    if (lane == 0) {
        int best = 0; float bv = acc[0];
#pragma unroll
        for (int e = 1; e < E_NUM; ++e) { if (acc[e] > bv) { bv = acc[e]; best = e; } }
        scale[t] = 1.f / (1.f + expf(-bv));
        int pos = atomicAdd(&counts[best], 1);
        buckets[best * T_TOK + pos] = t;
    }
}

// ---------------- 128-padded prefix offsets ----------------
__global__ void offs_kernel(const int* __restrict__ counts, int* __restrict__ offP) {
    if (threadIdx.x == 0) {
        int run = 0;
#pragma unroll
        for (int e = 0; e < E_NUM; ++e) { offP[e] = run; run += (counts[e] + 127) & ~127; }
        offP[E_NUM] = run;
    }
}

// ---------------- gather: xsg[slot] = bf16(scale[tok] * x[tok]) ----------------
__global__ __launch_bounds__(256) void gather_kernel(
    const float* __restrict__ x, const float* __restrict__ scale,
    const int* __restrict__ counts, const int* __restrict__ offP,
    const int* __restrict__ buckets, short* __restrict__ xsg,
    int* __restrict__ slot_tok)
{
    const int r = blockIdx.x;          // slot row 0..5119
    int e = 0;
#pragma unroll
    for (int k = 1; k < E_NUM; ++k) if (r >= offP[k]) e = k;
    const int pos = r - offP[e];
    const bool valid = (r < offP[E_NUM]) && (pos < counts[e]);
    const int tok = valid ? buckets[e * T_TOK + pos] : -1;
    if (threadIdx.x == 0) slot_tok[r] = tok;

    short* orow = xsg + (size_t)r * H_DIM + threadIdx.x * 8;
    if (!valid) {
        i32x4 z = {0, 0, 0, 0};
        *(i32x4*)orow = z;
        return;
    }
    const float sc = scale[tok];
    const float* xr = x + (size_t)tok * H_DIM + threadIdx.x * 8;
    float4 a = *(const float4*)xr;
    float4 b = *(const float4*)(xr + 4);
    short o[8] __attribute__((aligned(16)));
    o[0] = f2bf(a.x * sc); o[1] = f2bf(a.y * sc);
    o[2] = f2bf(a.z * sc); o[3] = f2bf(a.w * sc);
    o[4] = f2bf(b.x * sc); o[5] = f2bf(b.y * sc);
    o[6] = f2bf(b.z * sc); o[7] = f2bf(b.w * sc);
    *(i32x4*)orow = *(const i32x4*)o;
}

// ---------------- weight transpose + bf16 convert ----------------
// src: [E][K][N] f32  ->  dst: [E][N][K] bf16
__global__ __launch_bounds__(256) void transpose_cvt_kernel(
    const float* __restrict__ src, short* __restrict__ dst, int K, int N)
{
    __shared__ float s[64][65];
    const int e  = blockIdx.z;
    const int k0 = blockIdx.x * 64;
    const int n0 = blockIdx.y * 64;
    const int t  = threadIdx.x;

    const float* S = src + ((size_t)e * K + k0) * N + n0;
    const int kr = t >> 4, nc = (t & 15) * 4;
#pragma unroll
    for (int i = 0; i < 4; ++i) {
        float4 v = *(const float4*)(S + (size_t)(kr + i * 16) * N + nc);
        s[kr + i * 16][nc + 0] = v.x;
        s[kr + i * 16][nc + 1] = v.y;
        s[kr + i * 16][nc + 2] = v.z;
        s[kr + i * 16][nc + 3] = v.w;
    }
    __syncthreads();

    const int nr = t >> 2, kc = (t & 3) * 16;
    short tmp[16] __attribute__((aligned(16)));
#pragma unroll
    for (int j = 0; j < 16; ++j) tmp[j] = f2bf(s[kc + j][nr]);
    short* D = dst + ((size_t)e * N + n0 + nr) * K + k0 + kc;
    *(i32x4*)D       = *(const i32x4*)tmp;
    *(i32x4*)(D + 8) = *(const i32x4*)(tmp + 8);
}

// ---------------- grouped MFMA GEMM1 + SwiGLU (r3-proven 128x128 2-phase) ----
// A = xsg rows m0..m0+127 (dense), B = w1t[e] rows {f0..f0+63, I+f0..I+f0+63}
// 4 waves, wave = 32 rows x 128 B-rows (2 m-frags x 8 n-frags), BK=32, dbuf.
__global__ __launch_bounds__(256) void gemm1_mfma_kernel(
    const short* __restrict__ xsg, const short* __restrict__ w1t,
    const int* __restrict__ offP, short* __restrict__ act)
{
    __shared__ short sA[2][128 * 32];
    __shared__ short sB[2][128 * 32];

    const int bid = blockIdx.x;
    const int wg  = (bid & 7) * 80 + (bid >> 3);   // bijective: 640 % 8 == 0
    const int nt  = wg / MT;
    const int mt  = wg - nt * MT;
    const int m0  = mt << 7;
    if (m0 >= offP[E_NUM]) return;
    const int f0  = nt << 6;

    int e = 0;
#pragma unroll
    for (int k = 1; k < E_NUM; ++k) if (m0 >= offP[k]) e = k;

    const int tid = threadIdx.x, lane = tid & 63, w = tid >> 6;
    const int g = lane & 3, lr = lane >> 2;
    const int rA0 = (2 * w) * 16 + lr, rA1 = rA0 + 16;

    const short* srcA0 = xsg + (size_t)(m0 + rA0) * H_DIM + g * 8;
    const short* srcA1 = xsg + (size_t)(m0 + rA1) * H_DIM + g * 8;
    const int n0r = (rA0 < 64) ? (f0 + rA0) : (I_DIM + f0 + (rA0 & 63));
    const int n1r = (rA1 < 64) ? (f0 + rA1) : (I_DIM + f0 + (rA1 & 63));
    const short* srcB0 = w1t + ((size_t)e * TWO_I + n0r) * H_DIM + g * 8;
    const short* srcB1 = w1t + ((size_t)e * TWO_I + n1r) * H_DIM + g * 8;

    const int lm = lane & 15, lg8 = (lane >> 4) * 8;
    const int offA = (w * 32 + lm) * 32 + lg8;   // + mi*512
    const int offB = lm * 32 + lg8;              // + nf*512

    f32x4 acc[2][8];
#pragma unroll
    for (int i = 0; i < 2; ++i)
#pragma unroll
        for (int j = 0; j < 8; ++j) acc[i][j] = (f32x4){0.f, 0.f, 0.f, 0.f};

    auto STG = [&](int buf, int kb) {
        gload16(srcA0 + kb, &sA[buf][(2 * w) * 512]);
        gload16(srcA1 + kb, &sA[buf][(2 * w + 1) * 512]);
        gload16(srcB0 + kb, &sB[buf][(2 * w) * 512]);
        gload16(srcB1 + kb, &sB[buf][(2 * w + 1) * 512]);
    };
    auto CMP = [&](int buf) {
        const short* pA = &sA[buf][offA];
        const short* pB = &sB[buf][offB];
        bf16x8 a0 = *(const bf16x8*)pA;
        bf16x8 a1 = *(const bf16x8*)(pA + 512);
#pragma unroll
        for (int nf = 0; nf < 8; ++nf) {
            bf16x8 b = *(const bf16x8*)(pB + nf * 512);
            acc[0][nf] = __builtin_amdgcn_mfma_f32_16x16x32_bf16(a0, b, acc[0][nf], 0, 0, 0);
            acc[1][nf] = __builtin_amdgcn_mfma_f32_16x16x32_bf16(a1, b, acc[1][nf], 0, 0, 0);
        }
    };

    int cur = 0;
    STG(0, 0);
    for (int kb = 32; kb < H_DIM; kb += 32) {
        __syncthreads();          // drains vmcnt: staged cur is complete
        STG(cur ^ 1, kb);         // prefetch next tile (overlaps compute)
        CMP(cur);
        cur ^= 1;
    }
    __syncthreads();
    CMP(cur);

    // epilogue: act[slot] = up * gate * sigmoid(gate)
    const int rbase = w * 32 + (lane >> 4) * 4;
#pragma unroll
    for (int mi = 0; mi < 2; ++mi) {
#pragma unroll
        for (int rr = 0; rr < 4; ++rr) {
            const int row = rbase + mi * 16 + rr;
            short* orow = act + (size_t)(m0 + row) * I_DIM + f0 + lm;
#pragma unroll
            for (int nf = 0; nf < 4; ++nf) {
                float up = acc[mi][nf][rr];
                float gt = acc[mi][nf + 4][rr];
                float v  = up * gt / (1.f + expf(-gt));
                orow[nf * 16] = f2bf(v);
            }
        }
    }
}

// ---------------- grouped MFMA GEMM2 (dense slots -> scatter out) ----------
__global__ __launch_bounds__(256) void gemm2_mfma_kernel(
    const short* __restrict__ actm, const short* __restrict__ w2t,
    const int* __restrict__ offP, const int* __restrict__ slot_tok,
    float* __restrict__ out)
{
    __shared__ short sA[2][128 * 32];
    __shared__ short sB[2][128 * 32];
    __shared__ int   sTok[128];

    const int bid = blockIdx.x;
    const int wg  = (bid & 7) * 80 + (bid >> 3);
    const int nt  = wg / MT;
    const int mt  = wg - nt * MT;
    const int m0  = mt << 7;
    if (m0 >= offP[E_NUM]) return;
    const int h0  = nt << 7;

    int e = 0;
#pragma unroll
    for (int k = 1; k < E_NUM; ++k) if (m0 >= offP[k]) e = k;

    const int tid = threadIdx.x, lane = tid & 63, w = tid >> 6;
    if (tid < 128) sTok[tid] = slot_tok[m0 + tid];

    const int g = lane & 3, lr = lane >> 2;
    const int rA0 = (2 * w) * 16 + lr, rA1 = rA0 + 16;

    const short* srcA0 = actm + (size_t)(m0 + rA0) * I_DIM + g * 8;
    const short* srcA1 = actm + (size_t)(m0 + rA1) * I_DIM + g * 8;
    const short* srcB0 = w2t + ((size_t)e * H_DIM + h0 + rA0) * I_DIM + g * 8;
    const short* srcB1 = w2t + ((size_t)e * H_DIM + h0 + rA1) * I_DIM + g * 8;

    const int lm = lane & 15, lg8 = (lane >> 4) * 8;
    const int offA = (w * 32 + lm) * 32 + lg8;
    const int offB = lm * 32 + lg8;

    f32x4 acc[2][8];
#pragma unroll
    for (int i = 0; i < 2; ++i)
#pragma unroll
        for (int j = 0; j < 8; ++j) acc[i][j] = (f32x4){0.f, 0.f, 0.f, 0.f};

    auto STG = [&](int buf, int kb) {
        gload16(srcA0 + kb, &sA[buf][(2 * w) * 512]);
        gload16(srcA1 + kb, &sA[buf][(2 * w + 1) * 512]);
        gload16(srcB0 + kb, &sB[buf][(2 * w) * 512]);
        gload16(srcB1 + kb, &sB[buf][(2 * w + 1) * 512]);
    };
    auto CMP = [&](int buf) {
        const short* pA = &sA[buf][offA];
        const short* pB = &sB[buf][offB];
        bf16x8 a0 = *(const bf16x8*)pA;
        bf16x8 a1 = *(const bf16x8*)(pA + 512);
#pragma unroll
        for (int nf = 0; nf < 8; ++nf) {
            bf16x8 b = *(const bf16x8*)(pB + nf * 512);
            acc[0][nf] = __builtin_amdgcn_mfma_f32_16x16x32_bf16(a0, b, acc[0][nf], 0, 0, 0);
            acc[1][nf] = __builtin_amdgcn_mfma_f32_16x16x32_bf16(a1, b, acc[1][nf], 0, 0, 0);
        }
    };

    int cur = 0;
    STG(0, 0);
    for (int kb = 32; kb < I_DIM; kb += 32) {
        __syncthreads();
        STG(cur ^ 1, kb);
        CMP(cur);
        cur ^= 1;
    }
    __syncthreads();
    CMP(cur);

    const int rbase = w * 32 + (lane >> 4) * 4;
#pragma unroll
    for (int mi = 0; mi < 2; ++mi) {
#pragma unroll
        for (int rr = 0; rr < 4; ++rr) {
            const int row = rbase + mi * 16 + rr;
            const int tok = sTok[row];
            if (tok < 0) continue;
            float* orow = out + (size_t)tok * H_DIM + h0 + lm;
#pragma unroll
            for (int nf = 0; nf < 8; ++nf) orow[nf * 16] = acc[mi][nf][rr];
        }
    }
}

extern "C" void kernel_launch(void* const* d_in, const int* in_sizes, int n_in,
                              void* d_out, int out_size, void* d_ws, size_t ws_size,
                              hipStream_t stream) {
    const float* x   = (const float*)d_in[0];
    const float* gw  = (const float*)d_in[1];
    const float* gup = (const float*)d_in[2];
    const float* dw  = (const float*)d_in[3];
    float* out = (float*)d_out;

    char* ws = (char*)d_ws;
    float* scale    = (float*)(ws + WS_SCALE);
    int*   counts   = (int*)(ws + WS_COUNTS);
    int*   offP     = (int*)(ws + WS_OFFP);
    int*   buckets  = (int*)(ws + WS_BUCKETS);
    int*   slot_tok = (int*)(ws + WS_SLOTTOK);
    short* xsg      = (short*)(ws + WS_XSG);
    short* act      = (short*)(ws + WS_ACT);
    short* wt       = (short*)(ws + WS_WT);    // shared: w1t then w2t

    hipMemsetAsync(counts, 0, E_NUM * sizeof(int), stream);
    router_kernel<<<T_TOK / 4, 256, 0, stream>>>(x, gw, scale, counts, buckets);
    offs_kernel<<<1, 64, 0, stream>>>(counts, offP);
    gather_kernel<<<MROWS, 256, 0, stream>>>(x, scale, counts, offP, buckets, xsg, slot_tok);

    // w1t = transpose(gate_up_weight) bf16, then GEMM1 (+SwiGLU)
    dim3 gt1(H_DIM / 64, TWO_I / 64, E_NUM);
    transpose_cvt_kernel<<<gt1, 256, 0, stream>>>(gup, wt, H_DIM, TWO_I);
    gemm1_mfma_kernel<<<MT * 16, 256, 0, stream>>>(xsg, wt, offP, act);

    // w2t = transpose(down_weight) bf16 (reuses region), then GEMM2 (+scatter)
    dim3 gt2(I_DIM / 64, H_DIM / 64, E_NUM);
    transpose_cvt_kernel<<<gt2, 256, 0, stream>>>(dw, wt, I_DIM, H_DIM);
    gemm2_mfma_kernel<<<MT * 16, 256, 0, stream>>>(act, wt, offP, slot_tok, out);
}